// Round 1
// baseline (33.194 us; speedup 1.0000x reference)
//
#include <hip/hip_runtime.h>
#include <hip/hip_bf16.h>

// Quantum photonic classifier: x -> h -> phases -> U1 permanents (252) ->
// e1 -> Uf permanents (2002) -> linear head. All fp32, Ryser Gray-code
// permanents fully unrolled at compile time so fragments stay in registers.

__device__ __forceinline__ float2 cmul(float2 a, float2 b) {
    return make_float2(a.x * b.x - a.y * b.y, a.x * b.y + a.y * b.x);
}

// ---- Ryser (Gray code) permanent of a 5x5 complex matrix ----------------
// perm = sum_{s subset of cols, s!=0} (-1)^(5-|s|) prod_r (sum_{c in s} A[r][c])
// Step K toggles column ctz(K); everything constexpr so A[r][j] is a
// compile-time register access (no scratch).
template<int K>
__device__ __forceinline__ void ryser_step(float2 (&rs)[5], const float2 (&A)[5][5], float2& pm) {
    constexpr unsigned g    = (unsigned)K ^ ((unsigned)K >> 1);
    constexpr unsigned og   = (unsigned)(K - 1) ^ ((unsigned)(K - 1) >> 1);
    constexpr unsigned diff = g ^ og;
    constexpr int j = (diff & 1u) ? 0 : (diff & 2u) ? 1 : (diff & 4u) ? 2 : (diff & 8u) ? 3 : 4;
    constexpr bool add = (g & diff) != 0u;
#pragma unroll
    for (int r = 0; r < 5; ++r) {
        if constexpr (add) { rs[r].x += A[r][j].x; rs[r].y += A[r][j].y; }
        else               { rs[r].x -= A[r][j].x; rs[r].y -= A[r][j].y; }
    }
    float2 prod = cmul(cmul(cmul(cmul(rs[0], rs[1]), rs[2]), rs[3]), rs[4]);
    constexpr int pc = ((g >> 0) & 1) + ((g >> 1) & 1) + ((g >> 2) & 1) + ((g >> 3) & 1) + ((g >> 4) & 1);
    if constexpr (((5 - pc) & 1) != 0) { pm.x -= prod.x; pm.y -= prod.y; }
    else                               { pm.x += prod.x; pm.y += prod.y; }
}

template<int K>
__device__ __forceinline__ void ryser_all(float2 (&rs)[5], const float2 (&A)[5][5], float2& pm) {
    ryser_step<K>(rs, A, pm);
    if constexpr (K < 31) ryser_all<K + 1>(rs, A, pm);
}

__device__ __forceinline__ float2 perm5(const float2 (&A)[5][5]) {
    float2 rs[5];
#pragma unroll
    for (int r = 0; r < 5; ++r) rs[r] = make_float2(0.f, 0.f);
    float2 pm = make_float2(0.f, 0.f);
    ryser_all<1>(rs, A, pm);
    return pm;
}

// ---- K1: h = x @ Wd^T + bd ; D1 = exp(i h/pi) ; B1 = U1L diag(D1) U1R[:,even]
__global__ __launch_bounds__(256) void k_theta_B1(
    const float* __restrict__ x, const float* __restrict__ Wd, const float* __restrict__ bd,
    const float* __restrict__ U1L, const float* __restrict__ U1R, float2* __restrict__ B1) {
    const int n = blockIdx.x;
    const int tid = threadIdx.x;
    __shared__ float red[10][256];
    float acc[10];
#pragma unroll
    for (int j = 0; j < 10; ++j) acc[j] = 0.f;
    const float* xr = x + n * 784;
    for (int k = tid; k < 784; k += 256) {
        float xv = xr[k];
#pragma unroll
        for (int j = 0; j < 10; ++j) acc[j] = fmaf(xv, Wd[j * 784 + k], acc[j]);
    }
#pragma unroll
    for (int j = 0; j < 10; ++j) red[j][tid] = acc[j];
    __syncthreads();
    for (int off = 128; off > 0; off >>= 1) {
        if (tid < off) {
#pragma unroll
            for (int j = 0; j < 10; ++j) red[j][tid] += red[j][tid + off];
        }
        __syncthreads();
    }
    __shared__ float2 D[10];
    if (tid < 10) {
        float h = red[tid][0] + bd[tid];
        float th = h / 3.14159265358979323846f;
        float s, c;
        sincosf(th, &s, &c);
        D[tid] = make_float2(c, s);
    }
    __syncthreads();
    if (tid < 50) {
        const int i = tid / 5, cc = tid % 5, k = 2 * cc;
        float2 a = make_float2(0.f, 0.f);
#pragma unroll
        for (int j = 0; j < 10; ++j) {
            float2 ul = make_float2(U1L[(i * 10 + j) * 2], U1L[(i * 10 + j) * 2 + 1]);
            float2 ur = make_float2(U1R[(j * 10 + k) * 2], U1R[(j * 10 + k) * 2 + 1]);
            float2 t = cmul(cmul(ul, D[j]), ur);
            a.x += t.x; a.y += t.y;
        }
        B1[n * 50 + tid] = a;
    }
}

// ---- K2: 252 permanents -> p1 -> sum-normalize -> e1 -> D2 -> B2 ---------
__global__ __launch_bounds__(256) void k_circuit1(
    const float2* __restrict__ B1g, const int* __restrict__ rows1,
    const float* __restrict__ mask1, const float* __restrict__ UfL,
    const float* __restrict__ UfR, float2* __restrict__ B2g) {
    const int n = blockIdx.x;
    const int tid = threadIdx.x;
    __shared__ float2 B[50];
    __shared__ float p1s[256];
    __shared__ float red[256];
    if (tid < 50) B[tid] = B1g[n * 50 + tid];
    p1s[tid] = 0.f;
    __syncthreads();
    if (tid < 252) {
        int rr[5];
#pragma unroll
        for (int r = 0; r < 5; ++r) rr[r] = rows1[tid * 5 + r];
        float2 A[5][5];
#pragma unroll
        for (int r = 0; r < 5; ++r)
#pragma unroll
            for (int c = 0; c < 5; ++c) A[r][c] = B[rr[r] * 5 + c];
        float2 pm = perm5(A);
        p1s[tid] = pm.x * pm.x + pm.y * pm.y;
    }
    __syncthreads();
    red[tid] = p1s[tid];
    __syncthreads();
    for (int off = 128; off > 0; off >>= 1) {
        if (tid < off) red[tid] += red[tid + off];
        __syncthreads();
    }
    __shared__ float2 D2[10];
    if (tid < 10) {
        float a = 0.f;
        for (int p = 0; p < 252; ++p) a = fmaf(p1s[p], mask1[p * 10 + tid], a);
        float e = a / red[0];
        float s, c;
        sincosf(e, &s, &c);
        D2[tid] = make_float2(c, s);
    }
    __syncthreads();
    if (tid < 50) {
        const int i = tid / 5, cc = tid % 5, k = 2 * cc;
        float2 a = make_float2(0.f, 0.f);
#pragma unroll
        for (int j = 0; j < 10; ++j) {
            float2 ul = make_float2(UfL[(i * 10 + j) * 2], UfL[(i * 10 + j) * 2 + 1]);
            float2 ur = make_float2(UfR[(j * 10 + k) * 2], UfR[(j * 10 + k) * 2 + 1]);
            float2 t = cmul(cmul(ul, D2[j]), ur);
            a.x += t.x; a.y += t.y;
        }
        B2g[n * 50 + tid] = a;
    }
}

// ---- K3: 2002 permanents per sample (8 chunks) + partial dot with W_out --
__global__ __launch_bounds__(256) void k_circuit2(
    const float2* __restrict__ B2g, const int* __restrict__ rows2,
    const float* __restrict__ norm2, const float* __restrict__ Wout,
    float* __restrict__ partial) {
    const int n = blockIdx.x >> 3;
    const int chunk = blockIdx.x & 7;
    const int tid = threadIdx.x;
    __shared__ float2 B[50];
    __shared__ float r0[256], r1[256];
    if (tid < 50) B[tid] = B2g[n * 50 + tid];
    __syncthreads();
    const int p = chunk * 256 + tid;
    float f0 = 0.f, f1 = 0.f;
    if (p < 2002) {
        int rr[5];
#pragma unroll
        for (int r = 0; r < 5; ++r) rr[r] = rows2[p * 5 + r];
        float2 A[5][5];
#pragma unroll
        for (int r = 0; r < 5; ++r)
#pragma unroll
            for (int c = 0; c < 5; ++c) A[r][c] = B[rr[r] * 5 + c];
        float2 pm = perm5(A);
        float pf = (pm.x * pm.x + pm.y * pm.y) * norm2[p];
        f0 = pf * Wout[p];
        f1 = pf * Wout[2002 + p];
    }
    r0[tid] = f0;
    r1[tid] = f1;
    __syncthreads();
    for (int off = 128; off > 0; off >>= 1) {
        if (tid < off) { r0[tid] += r0[tid + off]; r1[tid] += r1[tid + off]; }
        __syncthreads();
    }
    if (tid == 0) {
        partial[(n * 8 + chunk) * 2 + 0] = r0[0];
        partial[(n * 8 + chunk) * 2 + 1] = r1[0];
    }
}

// ---- K4: reduce chunk partials + bias -> out (256,2) --------------------
__global__ __launch_bounds__(256) void k_final(
    const float* __restrict__ partial, const float* __restrict__ bout,
    float* __restrict__ out) {
    const int t = blockIdx.x * blockDim.x + threadIdx.x;
    if (t < 512) {
        const int n = t >> 1, o = t & 1;
        float a = bout[o];
#pragma unroll
        for (int c = 0; c < 8; ++c) a += partial[(n * 8 + c) * 2 + o];
        out[t] = a;
    }
}

extern "C" void kernel_launch(void* const* d_in, const int* in_sizes, int n_in,
                              void* d_out, int out_size, void* d_ws, size_t ws_size,
                              hipStream_t stream) {
    const float* x     = (const float*)d_in[0];
    const float* Wd    = (const float*)d_in[1];
    const float* bd    = (const float*)d_in[2];
    const float* U1L   = (const float*)d_in[3];
    const float* U1R   = (const float*)d_in[4];
    const float* UfL   = (const float*)d_in[5];
    const float* UfR   = (const float*)d_in[6];
    const float* Wout  = (const float*)d_in[7];
    const float* bout  = (const float*)d_in[8];
    const float* mask1 = (const float*)d_in[9];
    const float* norm2 = (const float*)d_in[10];
    const int*   rows1 = (const int*)d_in[11];
    const int*   rows2 = (const int*)d_in[12];
    float* out = (float*)d_out;

    char* ws = (char*)d_ws;
    float2* B1      = (float2*)(ws);            // 256*50*8  = 102400 B
    float2* B2      = (float2*)(ws + 102400);   // 102400 B
    float*  partial = (float*)(ws + 204800);    // 256*8*2*4 = 16384 B

    hipLaunchKernelGGL(k_theta_B1, dim3(256), dim3(256), 0, stream, x, Wd, bd, U1L, U1R, B1);
    hipLaunchKernelGGL(k_circuit1, dim3(256), dim3(256), 0, stream, B1, rows1, mask1, UfL, UfR, B2);
    hipLaunchKernelGGL(k_circuit2, dim3(2048), dim3(256), 0, stream, B2, rows2, norm2, Wout, partial);
    hipLaunchKernelGGL(k_final, dim3(2), dim3(256), 0, stream, partial, bout, out);
}

// Round 2
// 23.737 us; speedup vs baseline: 1.3984x; 1.3984x over previous
//
#include <hip/hip_runtime.h>
#include <hip/hip_bf16.h>

// Fully-fused quantum photonic classifier: one block per sample (256 blocks x
// 512 threads). x -> h -> D1 -> B1(LDS) -> 252 permanents -> e1 -> D2 ->
// B2(LDS) -> 2002 permanents -> dot(W_out) -> out. All intermediates stay in
// LDS/registers; single launch.

__device__ __forceinline__ float2 cmul(float2 a, float2 b) {
    return make_float2(fmaf(a.x, b.x, -a.y * b.y), fmaf(a.x, b.y, a.y * b.x));
}

// ---- Ryser (Gray code) permanent of a 5x5 complex matrix ----------------
// Fully unrolled: column index j is constexpr so A stays in registers.
template<int K>
__device__ __forceinline__ void ryser_step(float2 (&rs)[5], const float2 (&A)[5][5], float2& pm) {
    constexpr unsigned g    = (unsigned)K ^ ((unsigned)K >> 1);
    constexpr unsigned og   = (unsigned)(K - 1) ^ ((unsigned)(K - 1) >> 1);
    constexpr unsigned diff = g ^ og;
    constexpr int j = (diff & 1u) ? 0 : (diff & 2u) ? 1 : (diff & 4u) ? 2 : (diff & 8u) ? 3 : 4;
    constexpr bool add = (g & diff) != 0u;
#pragma unroll
    for (int r = 0; r < 5; ++r) {
        if constexpr (add) { rs[r].x += A[r][j].x; rs[r].y += A[r][j].y; }
        else               { rs[r].x -= A[r][j].x; rs[r].y -= A[r][j].y; }
    }
    float2 prod = cmul(cmul(cmul(cmul(rs[0], rs[1]), rs[2]), rs[3]), rs[4]);
    constexpr int pc = ((g >> 0) & 1) + ((g >> 1) & 1) + ((g >> 2) & 1) + ((g >> 3) & 1) + ((g >> 4) & 1);
    if constexpr (((5 - pc) & 1) != 0) { pm.x -= prod.x; pm.y -= prod.y; }
    else                               { pm.x += prod.x; pm.y += prod.y; }
}

template<int K>
__device__ __forceinline__ void ryser_all(float2 (&rs)[5], const float2 (&A)[5][5], float2& pm) {
    ryser_step<K>(rs, A, pm);
    if constexpr (K < 31) ryser_all<K + 1>(rs, A, pm);
}

__device__ __forceinline__ float2 perm5(const float2 (&A)[5][5]) {
    float2 rs[5];
#pragma unroll
    for (int r = 0; r < 5; ++r) rs[r] = make_float2(0.f, 0.f);
    float2 pm = make_float2(0.f, 0.f);
    ryser_all<1>(rs, A, pm);
    return pm;
}

__global__ __launch_bounds__(512) void k_fused(
    const float* __restrict__ x, const float* __restrict__ Wd, const float* __restrict__ bd,
    const float* __restrict__ U1L, const float* __restrict__ U1R,
    const float* __restrict__ UfL, const float* __restrict__ UfR,
    const float* __restrict__ Wout, const float* __restrict__ bout,
    const float* __restrict__ mask1, const float* __restrict__ norm2,
    const int* __restrict__ rows1, const int* __restrict__ rows2,
    float* __restrict__ out)
{
    const int n    = blockIdx.x;
    const int tid  = threadIdx.x;
    const int lane = tid & 63;
    const int wid  = tid >> 6;   // 8 waves

    __shared__ float2 Bsh[50];        // B1 then B2
    __shared__ float  p1s[256];
    __shared__ float2 Dsh[10];
    __shared__ float  sred[10][8];
    __shared__ float  epart[32][10];
    __shared__ float  tred[4];
    __shared__ float  fred[8][2];

    // ---- phase 1: h = x[n] @ Wd^T + bd -> D1 = exp(i h/pi) --------------
    float acc[10];
#pragma unroll
    for (int j = 0; j < 10; ++j) acc[j] = 0.f;
    const float* xr = x + n * 784;
    for (int k = tid; k < 784; k += 512) {
        float xv = xr[k];
#pragma unroll
        for (int j = 0; j < 10; ++j) acc[j] = fmaf(xv, Wd[j * 784 + k], acc[j]);
    }
#pragma unroll
    for (int off = 32; off > 0; off >>= 1)
#pragma unroll
        for (int j = 0; j < 10; ++j) acc[j] += __shfl_xor(acc[j], off, 64);
    if (lane == 0)
#pragma unroll
        for (int j = 0; j < 10; ++j) sred[j][wid] = acc[j];
    __syncthreads();
    if (tid < 10) {
        float h = bd[tid];
#pragma unroll
        for (int w = 0; w < 8; ++w) h += sred[tid][w];
        float s, c;
        sincosf(h * 0.31830988618379067154f, &s, &c);   // h / pi
        Dsh[tid] = make_float2(c, s);
    }
    __syncthreads();
    // B1 = U1L diag(D1) U1R[:, even]  (50 complex entries)
    if (tid < 50) {
        const int i = tid / 5, k = 2 * (tid % 5);
        float2 a = make_float2(0.f, 0.f);
#pragma unroll
        for (int j = 0; j < 10; ++j) {
            float2 ul = make_float2(U1L[(i * 10 + j) * 2], U1L[(i * 10 + j) * 2 + 1]);
            float2 ur = make_float2(U1R[(j * 10 + k) * 2], U1R[(j * 10 + k) * 2 + 1]);
            float2 t = cmul(cmul(ul, Dsh[j]), ur);
            a.x += t.x; a.y += t.y;
        }
        Bsh[tid] = a;
    }
    __syncthreads();

    // ---- phase 2: circuit-1 permanents (252) -> e1 -> D2 -> B2 ----------
    float p1 = 0.f;
    if (tid < 252) {
        int rr[5];
#pragma unroll
        for (int r = 0; r < 5; ++r) rr[r] = rows1[tid * 5 + r];
        float2 A[5][5];
#pragma unroll
        for (int r = 0; r < 5; ++r)
#pragma unroll
            for (int c = 0; c < 5; ++c) A[r][c] = Bsh[rr[r] * 5 + c];
        float2 pm = perm5(A);
        p1 = pm.x * pm.x + pm.y * pm.y;
    }
    if (tid < 256) p1s[tid] = p1;
    __syncthreads();
    // total = sum(p1)  (waves 0..3)
    if (tid < 256) {
        float v = p1s[tid];
#pragma unroll
        for (int off = 32; off > 0; off >>= 1) v += __shfl_xor(v, off, 64);
        if (lane == 0) tred[wid] = v;
    }
    // e1 partials: 320 threads, (chunk c of 8 perms) x (mode j)
    if (tid < 320) {
        const int c = tid / 10, j = tid - c * 10;
        float s = 0.f;
        const int p0 = c * 8, p1e = (p0 + 8 < 252) ? p0 + 8 : 252;
        for (int p = p0; p < p1e; ++p) s = fmaf(p1s[p], mask1[p * 10 + j], s);
        epart[c][j] = s;
    }
    __syncthreads();
    if (tid < 10) {
        const float total = tred[0] + tred[1] + tred[2] + tred[3];
        float e = 0.f;
#pragma unroll
        for (int c = 0; c < 32; ++c) e += epart[c][tid];
        e /= total;
        float s, cc;
        sincosf(e, &s, &cc);
        Dsh[tid] = make_float2(cc, s);
    }
    __syncthreads();
    if (tid < 50) {
        const int i = tid / 5, k = 2 * (tid % 5);
        float2 a = make_float2(0.f, 0.f);
#pragma unroll
        for (int j = 0; j < 10; ++j) {
            float2 ul = make_float2(UfL[(i * 10 + j) * 2], UfL[(i * 10 + j) * 2 + 1]);
            float2 ur = make_float2(UfR[(j * 10 + k) * 2], UfR[(j * 10 + k) * 2 + 1]);
            float2 t = cmul(cmul(ul, Dsh[j]), ur);
            a.x += t.x; a.y += t.y;
        }
        Bsh[tid] = a;   // overwrite with B2 (all B1 reads completed pre-sync)
    }
    __syncthreads();

    // ---- phase 3: circuit-2 permanents (2002) + dot with W_out ----------
    float f0 = 0.f, f1 = 0.f;
    for (int p = tid; p < 2002; p += 512) {
        int rr[5];
#pragma unroll
        for (int r = 0; r < 5; ++r) rr[r] = rows2[p * 5 + r];
        float2 A[5][5];
#pragma unroll
        for (int r = 0; r < 5; ++r)
#pragma unroll
            for (int c = 0; c < 5; ++c) A[r][c] = Bsh[rr[r] * 5 + c];
        float2 pm = perm5(A);
        float pf = (pm.x * pm.x + pm.y * pm.y) * norm2[p];
        f0 = fmaf(pf, Wout[p], f0);
        f1 = fmaf(pf, Wout[2002 + p], f1);
    }
#pragma unroll
    for (int off = 32; off > 0; off >>= 1) {
        f0 += __shfl_xor(f0, off, 64);
        f1 += __shfl_xor(f1, off, 64);
    }
    if (lane == 0) { fred[wid][0] = f0; fred[wid][1] = f1; }
    __syncthreads();
    if (tid < 2) {
        float a = bout[tid];
#pragma unroll
        for (int w = 0; w < 8; ++w) a += fred[w][tid];
        out[n * 2 + tid] = a;
    }
}

extern "C" void kernel_launch(void* const* d_in, const int* in_sizes, int n_in,
                              void* d_out, int out_size, void* d_ws, size_t ws_size,
                              hipStream_t stream) {
    const float* x     = (const float*)d_in[0];
    const float* Wd    = (const float*)d_in[1];
    const float* bd    = (const float*)d_in[2];
    const float* U1L   = (const float*)d_in[3];
    const float* U1R   = (const float*)d_in[4];
    const float* UfL   = (const float*)d_in[5];
    const float* UfR   = (const float*)d_in[6];
    const float* Wout  = (const float*)d_in[7];
    const float* bout  = (const float*)d_in[8];
    const float* mask1 = (const float*)d_in[9];
    const float* norm2 = (const float*)d_in[10];
    const int*   rows1 = (const int*)d_in[11];
    const int*   rows2 = (const int*)d_in[12];
    float* out = (float*)d_out;

    hipLaunchKernelGGL(k_fused, dim3(256), dim3(512), 0, stream,
                       x, Wd, bd, U1L, U1R, UfL, UfR, Wout, bout,
                       mask1, norm2, rows1, rows2, out);
}